// Round 1
// baseline (21.543 us; speedup 1.0000x reference)
//
#include <hip/hip_runtime.h>
#include <hip/hip_bf16.h>

// out[b, e] = relu(cos(qp[0,0]+qp[0,1])) * (W2[e,0]+W2[e,1]+W2[e,2]+W2[e,3]) + b2[e]
// Every batch row is identical -> compute 4 e-values per thread, broadcast-store.
// B=8192, E=2048, FF=8192, NQ=4, DEPTH=2.

__global__ __launch_bounds__(256) void qffn_broadcast_kernel(
    const float* __restrict__ W2,   // (E, FF) row-major
    const float* __restrict__ b2,   // (E,)
    const float* __restrict__ qp,   // (NQ, DEPTH) flat; we need qp[0], qp[1]
    float* __restrict__ out,        // (B, E) row-major
    int E, int FF, int B, int rows_per_block)
{
    // scalar quantum value (input-independent)
    float qv = cosf(qp[0] + qp[1]);
    qv = fmaxf(qv, 0.0f);   // relu

    // float4 column group this thread owns: covers e0 .. e0+3
    const int c  = blockIdx.x * blockDim.x + threadIdx.x;   // [0, E/4)
    const int e0 = c * 4;
    if (e0 >= E) return;

    // W2[e, 0..3] is a contiguous, 16B-aligned float4 at offset e*FF
    const float4 w0 = *reinterpret_cast<const float4*>(W2 + (size_t)(e0 + 0) * FF);
    const float4 w1 = *reinterpret_cast<const float4*>(W2 + (size_t)(e0 + 1) * FF);
    const float4 w2 = *reinterpret_cast<const float4*>(W2 + (size_t)(e0 + 2) * FF);
    const float4 w3 = *reinterpret_cast<const float4*>(W2 + (size_t)(e0 + 3) * FF);
    const float4 bb = *reinterpret_cast<const float4*>(b2 + e0);

    float4 r;
    r.x = qv * (w0.x + w0.y + w0.z + w0.w) + bb.x;
    r.y = qv * (w1.x + w1.y + w1.z + w1.w) + bb.y;
    r.z = qv * (w2.x + w2.y + w2.z + w2.w) + bb.z;
    r.w = qv * (w3.x + w3.y + w3.z + w3.w) + bb.w;

    // broadcast-store into this block's slice of batch rows
    float4* __restrict__ outv = reinterpret_cast<float4*>(out);
    const size_t row_stride = (size_t)(E / 4);
    const int b_begin = blockIdx.y * rows_per_block;
    int b_end = b_begin + rows_per_block;
    if (b_end > B) b_end = B;

    #pragma unroll 4
    for (int b = b_begin; b < b_end; ++b) {
        outv[(size_t)b * row_stride + c] = r;
    }
}

extern "C" void kernel_launch(void* const* d_in, const int* in_sizes, int n_in,
                              void* d_out, int out_size, void* d_ws, size_t ws_size,
                              hipStream_t stream)
{
    // inputs (setup_inputs order): x, W1, b1, W2, b2, q_params
    const float* W2 = (const float*)d_in[3];
    const float* b2 = (const float*)d_in[4];
    const float* qp = (const float*)d_in[5];
    float* out = (float*)d_out;

    const int E  = in_sizes[4];            // 2048 (len of b2)
    const int FF = in_sizes[2];            // 8192 (len of b1)
    const int B  = out_size / E;           // 8192

    const int threads = 256;
    const int rows_per_block = 8;
    dim3 grid((E / 4 + threads - 1) / threads,   // 2
              (B + rows_per_block - 1) / rows_per_block);  // 1024
    dim3 block(threads);

    qffn_broadcast_kernel<<<grid, block, 0, stream>>>(W2, b2, qp, out, E, FF, B, rows_per_block);
}

// Round 3
// 21.421 us; speedup vs baseline: 1.0057x; 1.0057x over previous
//
#include <hip/hip_runtime.h>
#include <hip/hip_bf16.h>

// out[b, e] = relu(cos(qp[0]+qp[1])) * (W2[e,0]+W2[e,1]+W2[e,2]+W2[e,3]) + b2[e]
// Every batch row is identical -> compute 4 e-values per thread, broadcast-store.
// B=8192, E=2048, FF=8192. Pure store-BW-bound: 64 MiB of f32 stores.

typedef float v4f __attribute__((ext_vector_type(4)));   // clang vector type: OK for nontemporal builtin

__global__ __launch_bounds__(256) void qffn_broadcast_kernel(
    const float* __restrict__ W2,   // (E, FF) row-major
    const float* __restrict__ b2,   // (E,)
    const float* __restrict__ qp,   // (NQ, DEPTH) flat; need qp[0], qp[1]
    float* __restrict__ out,        // (B, E) row-major
    int E, int FF, int B, int rows_per_block)
{
    // float4 column group this thread owns: covers e0 .. e0+3
    const int c  = blockIdx.x * blockDim.x + threadIdx.x;   // [0, E/4)
    const int e0 = c * 4;

    // Issue all global loads first (independent; latency overlaps).
    const v4f w0 = *reinterpret_cast<const v4f*>(W2 + (size_t)(e0 + 0) * FF);
    const v4f w1 = *reinterpret_cast<const v4f*>(W2 + (size_t)(e0 + 1) * FF);
    const v4f w2 = *reinterpret_cast<const v4f*>(W2 + (size_t)(e0 + 2) * FF);
    const v4f w3 = *reinterpret_cast<const v4f*>(W2 + (size_t)(e0 + 3) * FF);
    const v4f bb = *reinterpret_cast<const v4f*>(b2 + e0);
    const float q0 = qp[0];
    const float q1 = qp[1];

    float qv = fmaxf(cosf(q0 + q1), 0.0f);   // relu(cos(sum))

    v4f r;
    r.x = qv * (w0.x + w0.y + w0.z + w0.w) + bb.x;
    r.y = qv * (w1.x + w1.y + w1.z + w1.w) + bb.y;
    r.z = qv * (w2.x + w2.y + w2.z + w2.w) + bb.z;
    r.w = qv * (w3.x + w3.y + w3.z + w3.w) + bb.w;

    // broadcast-store into this block's slice of batch rows (streaming/nt)
    const size_t row_stride = (size_t)(E / 4);
    v4f* base =
        reinterpret_cast<v4f*>(out) + (size_t)blockIdx.y * rows_per_block * row_stride + c;

    #pragma unroll
    for (int i = 0; i < 8; ++i) {   // rows_per_block == 8, fully unrolled
        __builtin_nontemporal_store(r, base + (size_t)i * row_stride);
    }
}

extern "C" void kernel_launch(void* const* d_in, const int* in_sizes, int n_in,
                              void* d_out, int out_size, void* d_ws, size_t ws_size,
                              hipStream_t stream)
{
    // inputs (setup_inputs order): x, W1, b1, W2, b2, q_params
    const float* W2 = (const float*)d_in[3];
    const float* b2 = (const float*)d_in[4];
    const float* qp = (const float*)d_in[5];
    float* out = (float*)d_out;

    const int E  = in_sizes[4];            // 2048 (len of b2)
    const int FF = in_sizes[2];            // 8192 (len of b1)
    const int B  = out_size / E;           // 8192

    const int threads = 256;
    const int rows_per_block = 8;          // keep in sync with unroll above
    dim3 grid(E / 4 / threads,             // 2
              B / rows_per_block);         // 1024  -> 2048 blocks = 8/CU, full occupancy
    dim3 block(threads);

    qffn_broadcast_kernel<<<grid, block, 0, stream>>>(W2, b2, qp, out, E, FF, B, rows_per_block);
}